// Round 1
// baseline (194.108 us; speedup 1.0000x reference)
//
#include <hip/hip_runtime.h>
#include <math.h>

#define BATCH 64
#define SEQ   101
#define HID   512
#define NKQ   100      // N*K
#define KCLS  10
#define INV_TEMP 0.04419417382415922f   // 1/sqrt(512)

// ---------------- Kernel 1: scores = q k^T / temp, softmax -> attn ----------
// grid (4, BATCH), block 256. Block tile: TI=32 rows x all 101 cols.
#define TI 32
#define TJ 32
#define HC 128
#define LSTR 132      // LDS row stride (floats) for 128-float chunks (+4 pad)
#define SCSTR 104

__global__ __launch_bounds__(256)
void scores_softmax(const float* __restrict__ q, const float* __restrict__ k,
                    float* __restrict__ attn) {
    __shared__ float qs[TI * LSTR];   // 16.9 KB
    __shared__ float ks[TJ * LSTR];   // 16.9 KB
    __shared__ float sc[TI * SCSTR];  // 13.3 KB
    const int b  = blockIdx.y;
    const int i0 = blockIdx.x * TI;
    const int tid  = threadIdx.x;
    const int tj_g = tid & 15;   // 0..15
    const int ti_g = tid >> 4;   // 0..15

    const float* qb = q + (size_t)b * SEQ * HID;
    const float* kb = k + (size_t)b * SEQ * HID;

    for (int jc = 0; jc < 4; ++jc) {
        const int j0 = jc * TJ;
        float a00 = 0.f, a01 = 0.f, a10 = 0.f, a11 = 0.f;
        for (int hc = 0; hc < HID; hc += HC) {
            // stage q tile + k tile (32 rows x 128 floats each)
            #pragma unroll
            for (int t = 0; t < 4; ++t) {
                int e4 = tid + t * 256;        // float4 id 0..1023
                int r  = e4 >> 5;              // row 0..31
                int c  = (e4 & 31) << 2;       // float col 0..124
                float4 qv = make_float4(0.f, 0.f, 0.f, 0.f);
                int gi = i0 + r;
                if (gi < SEQ) qv = *(const float4*)(qb + (size_t)gi * HID + hc + c);
                *(float4*)(qs + r * LSTR + c) = qv;
                float4 kv = make_float4(0.f, 0.f, 0.f, 0.f);
                int gj = j0 + r;
                if (gj < SEQ) kv = *(const float4*)(kb + (size_t)gj * HID + hc + c);
                *(float4*)(ks + r * LSTR + c) = kv;
            }
            __syncthreads();
            const float* qa  = qs + (ti_g * 2) * LSTR;
            const float* qbp = qa + LSTR;
            const float* ka  = ks + (tj_g * 2) * LSTR;
            const float* kbp = ka + LSTR;
            #pragma unroll
            for (int h = 0; h < HC; h += 4) {
                float4 qa4 = *(const float4*)(qa + h);
                float4 qb4 = *(const float4*)(qbp + h);
                float4 ka4 = *(const float4*)(ka + h);
                float4 kb4 = *(const float4*)(kbp + h);
                a00 += qa4.x*ka4.x + qa4.y*ka4.y + qa4.z*ka4.z + qa4.w*ka4.w;
                a01 += qa4.x*kb4.x + qa4.y*kb4.y + qa4.z*kb4.z + qa4.w*kb4.w;
                a10 += qb4.x*ka4.x + qb4.y*ka4.y + qb4.z*ka4.z + qb4.w*ka4.w;
                a11 += qb4.x*kb4.x + qb4.y*kb4.y + qb4.z*kb4.z + qb4.w*kb4.w;
            }
            __syncthreads();
        }
        const int il = ti_g * 2;
        const int jl = j0 + tj_g * 2;
        if (jl < SEQ) {
            sc[il * SCSTR + jl]       = a00;
            sc[(il + 1) * SCSTR + jl] = a10;
        }
        if (jl + 1 < SEQ) {
            sc[il * SCSTR + jl + 1]       = a01;
            sc[(il + 1) * SCSTR + jl + 1] = a11;
        }
    }
    __syncthreads();

    // softmax: 8 threads per row (32 rows x 8 = 256)
    const int row = tid >> 3;
    const int l8  = tid & 7;
    const int gi  = i0 + row;
    float m = -1e30f;
    for (int j = l8; j < SEQ; j += 8) {
        float s = sc[row * SCSTR + j] * INV_TEMP;
        sc[row * SCSTR + j] = s;
        m = fmaxf(m, s);
    }
    #pragma unroll
    for (int off = 1; off < 8; off <<= 1) m = fmaxf(m, __shfl_xor(m, off));
    float sum = 0.f;
    for (int j = l8; j < SEQ; j += 8) {
        float e = __expf(sc[row * SCSTR + j] - m);
        sc[row * SCSTR + j] = e;
        sum += e;
    }
    #pragma unroll
    for (int off = 1; off < 8; off <<= 1) sum += __shfl_xor(sum, off);
    const float inv = 1.f / sum;
    if (gi < SEQ) {
        float* arow = attn + ((size_t)b * SEQ + gi) * SEQ;
        for (int j = l8; j < SEQ; j += 8) arow[j] = sc[row * SCSTR + j] * inv;
    }
}

// ---------------- Kernel 2: out = sum_j attn * w[idx] * v  -------------------
// Decomposition (i<100):  out = w2*T + (w1-w2)*Scls + (w0-w1)*a_ii*v_i + (w3-w2)*a_iN*v_N
//              (i==100): out = w4*T + (w5-w4)*a_NN*v_N
// grid (16 h-chunks of 32, BATCH), block 256
#define HC2  32
#define VSTR 36   // 8 float4 per row + 1 float4 pad

__global__ __launch_bounds__(256)
void weighted_out(const float* __restrict__ v, const float* __restrict__ aw,
                  const float* __restrict__ attn, float* __restrict__ out) {
    __shared__ float a_s[SEQ * SEQ];    // 40.8 KB
    __shared__ float v_s[SEQ * VSTR];   // 14.5 KB
    const int b   = blockIdx.y;
    const int hc  = blockIdx.x * HC2;
    const int tid = threadIdx.x;

    // stage attn[b] (full 101x101)
    const float* ab = attn + (size_t)b * SEQ * SEQ;
    for (int e = tid; e < SEQ * SEQ; e += 256) a_s[e] = ab[e];
    // stage v[:, hc:hc+32]
    const float* vb = v + (size_t)b * SEQ * HID + hc;
    for (int e4 = tid; e4 < SEQ * 8; e4 += 256) {
        int r = e4 >> 3;
        int c = (e4 & 7) << 2;
        *(float4*)(v_s + r * VSTR + c) = *(const float4*)(vb + (size_t)r * HID + c);
    }
    __syncthreads();

    const int h_off = (tid & 7) << 2;   // 0..28
    const int i_g   = tid >> 3;         // 0..31
    const float* vs_h = v_s + h_off;

    // weight slices for this thread's 4 h's (register-resident)
    const float* awh = aw + hc + h_off;
    const float4 w0 = *(const float4*)(awh + 0 * HID);
    const float4 w1 = *(const float4*)(awh + 1 * HID);
    const float4 w2 = *(const float4*)(awh + 2 * HID);
    const float4 w3 = *(const float4*)(awh + 3 * HID);
    const float4 w4 = *(const float4*)(awh + 4 * HID);
    const float4 w5 = *(const float4*)(awh + 5 * HID);

    const float4 vN = *(const float4*)(vs_h + NKQ * VSTR);
    float* ob = out + (size_t)b * SEQ * HID + hc + h_off;

    for (int i = i_g; i < SEQ; i += 32) {
        const float* arow = a_s + i * SEQ;
        float4 T; T.x = T.y = T.z = T.w = 0.f;
        #pragma unroll 4
        for (int j = 0; j < SEQ; ++j) {
            float a = arow[j];
            float4 vv = *(const float4*)(vs_h + j * VSTR);
            T.x = fmaf(a, vv.x, T.x);
            T.y = fmaf(a, vv.y, T.y);
            T.z = fmaf(a, vv.z, T.z);
            T.w = fmaf(a, vv.w, T.w);
        }
        const float aiN = arow[NKQ];
        float4 o;
        if (i < NKQ) {
            const int c0 = (i / KCLS) * KCLS;
            float4 Sc; Sc.x = Sc.y = Sc.z = Sc.w = 0.f;
            #pragma unroll
            for (int jj = 0; jj < KCLS; ++jj) {
                float a = arow[c0 + jj];
                float4 vv = *(const float4*)(vs_h + (c0 + jj) * VSTR);
                Sc.x = fmaf(a, vv.x, Sc.x);
                Sc.y = fmaf(a, vv.y, Sc.y);
                Sc.z = fmaf(a, vv.z, Sc.z);
                Sc.w = fmaf(a, vv.w, Sc.w);
            }
            const float aii = arow[i];
            const float4 vi = *(const float4*)(vs_h + i * VSTR);
            o.x = w2.x*T.x + (w1.x-w2.x)*Sc.x + (w0.x-w1.x)*aii*vi.x + (w3.x-w2.x)*aiN*vN.x;
            o.y = w2.y*T.y + (w1.y-w2.y)*Sc.y + (w0.y-w1.y)*aii*vi.y + (w3.y-w2.y)*aiN*vN.y;
            o.z = w2.z*T.z + (w1.z-w2.z)*Sc.z + (w0.z-w1.z)*aii*vi.z + (w3.z-w2.z)*aiN*vN.z;
            o.w = w2.w*T.w + (w1.w-w2.w)*Sc.w + (w0.w-w1.w)*aii*vi.w + (w3.w-w2.w)*aiN*vN.w;
        } else {
            // i == 100: a_NN == aiN here
            o.x = w4.x*T.x + (w5.x-w4.x)*aiN*vN.x;
            o.y = w4.y*T.y + (w5.y-w4.y)*aiN*vN.y;
            o.z = w4.z*T.z + (w5.z-w4.z)*aiN*vN.z;
            o.w = w4.w*T.w + (w5.w-w4.w)*aiN*vN.w;
        }
        *(float4*)(ob + (size_t)i * HID) = o;
    }
}

extern "C" void kernel_launch(void* const* d_in, const int* in_sizes, int n_in,
                              void* d_out, int out_size, void* d_ws, size_t ws_size,
                              hipStream_t stream) {
    const float* q  = (const float*)d_in[0];
    const float* k  = (const float*)d_in[1];
    const float* v  = (const float*)d_in[2];
    const float* aw = (const float*)d_in[3];
    // d_in[4]=N, d_in[5]=K — fixed at 10 by the problem instance (out_size matches S=101)
    float* out  = (float*)d_out;
    float* attn = out + (size_t)BATCH * SEQ * HID;   // tuple output: [out | attn]

    dim3 blk(256);
    dim3 g1(4, BATCH);
    scores_softmax<<<g1, blk, 0, stream>>>(q, k, attn);
    dim3 g2(HID / HC2, BATCH);
    weighted_out<<<g2, blk, 0, stream>>>(v, aw, attn, out);
}

// Round 2
// 169.035 us; speedup vs baseline: 1.1483x; 1.1483x over previous
//
#include <hip/hip_runtime.h>
#include <math.h>

#define BATCH 64
#define SEQ   101
#define HID   512
#define NKQ   100      // N*K
#define KCLS  10
#define INV_TEMP 0.04419417382415922f   // 1/sqrt(512)

// ---------------- Kernel 1: scores = q k^T (raw, no temp) --------------------
// grid (2 jt, 2 it, BATCH), block 256. Tile 64x64, 4x4 per thread.
// LDS tiles stored transposed: qT[k][i], kT[k][j] -> per k-step two b128 reads.
#define KC 32
#define TSTR 68   // padded row stride (floats); 68*4=272 B, 16B-aligned rows

__global__ __launch_bounds__(256)
void gemm_qk(const float* __restrict__ q, const float* __restrict__ k,
             float* __restrict__ sc) {
    __shared__ float qT[KC][TSTR];   // 8.7 KB
    __shared__ float kT[KC][TSTR];   // 8.7 KB
    const int b  = blockIdx.z;
    const int i0 = blockIdx.y * 64;
    const int j0 = blockIdx.x * 64;
    const int tid = threadIdx.x;
    const int ig = tid >> 4;   // 0..15 -> 4 i's
    const int jg = tid & 15;   // 0..15 -> 4 j's

    const float* qb = q + (size_t)b * SEQ * HID;
    const float* kb = k + (size_t)b * SEQ * HID;

    float acc[4][4];
    #pragma unroll
    for (int r = 0; r < 4; ++r)
        #pragma unroll
        for (int c = 0; c < 4; ++c) acc[r][c] = 0.f;

    for (int kc = 0; kc < HID; kc += KC) {
        // stage + transpose: 64 rows x 32 k each, 512 float4 per matrix
        #pragma unroll
        for (int s = 0; s < 2; ++s) {
            int f = tid + s * 256;       // 0..511
            int r = f >> 3;              // row 0..63
            int c = (f & 7) << 2;        // k-col 0,4,..,28
            int gi = i0 + r;
            float4 qv = make_float4(0.f, 0.f, 0.f, 0.f);
            if (gi < SEQ) qv = *(const float4*)(qb + (size_t)gi * HID + kc + c);
            qT[c + 0][r] = qv.x; qT[c + 1][r] = qv.y;
            qT[c + 2][r] = qv.z; qT[c + 3][r] = qv.w;
            int gj = j0 + r;
            float4 kv = make_float4(0.f, 0.f, 0.f, 0.f);
            if (gj < SEQ) kv = *(const float4*)(kb + (size_t)gj * HID + kc + c);
            kT[c + 0][r] = kv.x; kT[c + 1][r] = kv.y;
            kT[c + 2][r] = kv.z; kT[c + 3][r] = kv.w;
        }
        __syncthreads();
        #pragma unroll
        for (int kk = 0; kk < KC; ++kk) {
            float4 qv = *(const float4*)&qT[kk][ig << 2];
            float4 kv = *(const float4*)&kT[kk][jg << 2];
            acc[0][0] = fmaf(qv.x, kv.x, acc[0][0]);
            acc[0][1] = fmaf(qv.x, kv.y, acc[0][1]);
            acc[0][2] = fmaf(qv.x, kv.z, acc[0][2]);
            acc[0][3] = fmaf(qv.x, kv.w, acc[0][3]);
            acc[1][0] = fmaf(qv.y, kv.x, acc[1][0]);
            acc[1][1] = fmaf(qv.y, kv.y, acc[1][1]);
            acc[1][2] = fmaf(qv.y, kv.z, acc[1][2]);
            acc[1][3] = fmaf(qv.y, kv.w, acc[1][3]);
            acc[2][0] = fmaf(qv.z, kv.x, acc[2][0]);
            acc[2][1] = fmaf(qv.z, kv.y, acc[2][1]);
            acc[2][2] = fmaf(qv.z, kv.z, acc[2][2]);
            acc[2][3] = fmaf(qv.z, kv.w, acc[2][3]);
            acc[3][0] = fmaf(qv.w, kv.x, acc[3][0]);
            acc[3][1] = fmaf(qv.w, kv.y, acc[3][1]);
            acc[3][2] = fmaf(qv.w, kv.z, acc[3][2]);
            acc[3][3] = fmaf(qv.w, kv.w, acc[3][3]);
        }
        __syncthreads();
    }
    // store raw scores (rows are 101 floats -> not 16B aligned; scalar stores)
    #pragma unroll
    for (int r = 0; r < 4; ++r) {
        int gi = i0 + (ig << 2) + r;
        if (gi >= SEQ) continue;
        float* srow = sc + ((size_t)b * SEQ + gi) * SEQ;
        int gj = j0 + (jg << 2);
        #pragma unroll
        for (int c = 0; c < 4; ++c)
            if (gj + c < SEQ) srow[gj + c] = acc[r][c];
    }
}

// ---------------- Kernel 2: in-place row softmax (with 1/temp) ---------------
// one wave per row; 4 waves/block; grid = 6464/4 = 1616
__global__ __launch_bounds__(256)
void softmax_rows(float* __restrict__ attn) {
    const int lane = threadIdx.x & 63;
    const int wv   = threadIdx.x >> 6;
    const int row  = blockIdx.x * 4 + wv;   // 0..6463
    float* p = attn + (size_t)row * SEQ;
    float s0 = (lane < SEQ) ? p[lane] * INV_TEMP : -1e30f;
    float s1 = (lane + 64 < SEQ) ? p[lane + 64] * INV_TEMP : -1e30f;
    float m = fmaxf(s0, s1);
    #pragma unroll
    for (int off = 1; off < 64; off <<= 1) m = fmaxf(m, __shfl_xor(m, off));
    float e0 = __expf(s0 - m);
    float e1 = __expf(s1 - m);
    float sum = e0 + e1;
    #pragma unroll
    for (int off = 1; off < 64; off <<= 1) sum += __shfl_xor(sum, off);
    float inv = 1.f / sum;
    if (lane < SEQ) p[lane] = e0 * inv;
    if (lane + 64 < SEQ) p[lane + 64] = e1 * inv;
}

// ---------------- Kernel 3: out = region-decomposed contraction --------------
// out(i<100) = w2*T + (w1-w2)*Scls + (w0-w1)*a_ii*v_i + (w3-w2)*a_iN*v_N
// out(i=100) = w4*T + (w5-w4)*a_NN*v_N,   T = attn@v
// grid (8 hc of 64, 2 it of 64, BATCH), block 256, 4i x 4h per thread.
#define ASTR 68
#define VSTR 68

__global__ __launch_bounds__(256)
void weighted_out(const float* __restrict__ v, const float* __restrict__ aw,
                  const float* __restrict__ attn, float* __restrict__ out) {
    __shared__ float a_t[SEQ][ASTR];   // a_t[j][i_local], 27.5 KB
    __shared__ float v_s[SEQ][VSTR];   // v_s[j][h_local], 27.5 KB
    const int b   = blockIdx.z;
    const int i0  = blockIdx.y * 64;
    const int hc  = blockIdx.x * 64;
    const int tid = threadIdx.x;
    const int ig = tid >> 4;   // 0..15 -> 4 i's
    const int hg = tid & 15;   // 0..15 -> 4 h's

    // stage attn tile transposed: read [i][j] coalesced, write a_t[j][il]
    const float* ab = attn + (size_t)b * SEQ * SEQ;
    for (int e = tid; e < 64 * SEQ; e += 256) {
        int il = e / SEQ;
        int j  = e - il * SEQ;
        int gi = i0 + il;
        a_t[j][il] = (gi < SEQ) ? ab[(size_t)gi * SEQ + j] : 0.f;
    }
    // stage v[:, hc:hc+64]
    const float* vb = v + (size_t)b * SEQ * HID + hc;
    for (int f = tid; f < SEQ * 16; f += 256) {
        int r = f >> 4;
        int c = (f & 15) << 2;
        *(float4*)&v_s[r][c] = *(const float4*)(vb + (size_t)r * HID + c);
    }
    __syncthreads();

    float T[4][4];
    #pragma unroll
    for (int r = 0; r < 4; ++r)
        #pragma unroll
        for (int c = 0; c < 4; ++c) T[r][c] = 0.f;

    #pragma unroll 4
    for (int j = 0; j < SEQ; ++j) {
        float4 av = *(const float4*)&a_t[j][ig << 2];
        float4 vv = *(const float4*)&v_s[j][hg << 2];
        T[0][0] = fmaf(av.x, vv.x, T[0][0]);
        T[0][1] = fmaf(av.x, vv.y, T[0][1]);
        T[0][2] = fmaf(av.x, vv.z, T[0][2]);
        T[0][3] = fmaf(av.x, vv.w, T[0][3]);
        T[1][0] = fmaf(av.y, vv.x, T[1][0]);
        T[1][1] = fmaf(av.y, vv.y, T[1][1]);
        T[1][2] = fmaf(av.y, vv.z, T[1][2]);
        T[1][3] = fmaf(av.y, vv.w, T[1][3]);
        T[2][0] = fmaf(av.z, vv.x, T[2][0]);
        T[2][1] = fmaf(av.z, vv.y, T[2][1]);
        T[2][2] = fmaf(av.z, vv.z, T[2][2]);
        T[2][3] = fmaf(av.z, vv.w, T[2][3]);
        T[3][0] = fmaf(av.w, vv.x, T[3][0]);
        T[3][1] = fmaf(av.w, vv.y, T[3][1]);
        T[3][2] = fmaf(av.w, vv.z, T[3][2]);
        T[3][3] = fmaf(av.w, vv.w, T[3][3]);
    }

    // weight slices (4 h's), register-resident
    const float* awh = aw + hc + (hg << 2);
    const float4 w0 = *(const float4*)(awh + 0 * HID);
    const float4 w1 = *(const float4*)(awh + 1 * HID);
    const float4 w2 = *(const float4*)(awh + 2 * HID);
    const float4 w3 = *(const float4*)(awh + 3 * HID);
    const float4 w4 = *(const float4*)(awh + 4 * HID);
    const float4 w5 = *(const float4*)(awh + 5 * HID);
    const float4 vN = *(const float4*)&v_s[NKQ][hg << 2];

    #pragma unroll
    for (int r = 0; r < 4; ++r) {
        const int il = (ig << 2) + r;
        const int gi = i0 + il;
        if (gi >= SEQ) continue;
        const float aiN = a_t[NKQ][il];
        float4 o;
        if (gi < NKQ) {
            const int c0 = (gi / KCLS) * KCLS;
            float4 Sc = make_float4(0.f, 0.f, 0.f, 0.f);
            #pragma unroll
            for (int jj = 0; jj < KCLS; ++jj) {
                float a = a_t[c0 + jj][il];
                float4 vv = *(const float4*)&v_s[c0 + jj][hg << 2];
                Sc.x = fmaf(a, vv.x, Sc.x);
                Sc.y = fmaf(a, vv.y, Sc.y);
                Sc.z = fmaf(a, vv.z, Sc.z);
                Sc.w = fmaf(a, vv.w, Sc.w);
            }
            const float aii = a_t[gi][il];
            const float4 vi = *(const float4*)&v_s[gi][hg << 2];
            o.x = w2.x*T[r][0] + (w1.x-w2.x)*Sc.x + (w0.x-w1.x)*aii*vi.x + (w3.x-w2.x)*aiN*vN.x;
            o.y = w2.y*T[r][1] + (w1.y-w2.y)*Sc.y + (w0.y-w1.y)*aii*vi.y + (w3.y-w2.y)*aiN*vN.y;
            o.z = w2.z*T[r][2] + (w1.z-w2.z)*Sc.z + (w0.z-w1.z)*aii*vi.z + (w3.z-w2.z)*aiN*vN.z;
            o.w = w2.w*T[r][3] + (w1.w-w2.w)*Sc.w + (w0.w-w1.w)*aii*vi.w + (w3.w-w2.w)*aiN*vN.w;
        } else {
            o.x = w4.x*T[r][0] + (w5.x-w4.x)*aiN*vN.x;
            o.y = w4.y*T[r][1] + (w5.y-w4.y)*aiN*vN.y;
            o.z = w4.z*T[r][2] + (w5.z-w4.z)*aiN*vN.z;
            o.w = w4.w*T[r][3] + (w5.w-w4.w)*aiN*vN.w;
        }
        *(float4*)(out + ((size_t)b * SEQ + gi) * HID + hc + (hg << 2)) = o;
    }
}

extern "C" void kernel_launch(void* const* d_in, const int* in_sizes, int n_in,
                              void* d_out, int out_size, void* d_ws, size_t ws_size,
                              hipStream_t stream) {
    const float* q  = (const float*)d_in[0];
    const float* k  = (const float*)d_in[1];
    const float* v  = (const float*)d_in[2];
    const float* aw = (const float*)d_in[3];
    float* out  = (float*)d_out;
    float* attn = out + (size_t)BATCH * SEQ * HID;   // tuple output: [out | attn]

    dim3 blk(256);
    dim3 g1(2, 2, BATCH);
    gemm_qk<<<g1, blk, 0, stream>>>(q, k, attn);      // raw scores into attn slot
    softmax_rows<<<dim3(BATCH * SEQ / 4), blk, 0, stream>>>(attn);
    dim3 g3(8, 2, BATCH);
    weighted_out<<<g3, blk, 0, stream>>>(v, aw, attn, out);
}

// Round 3
// 164.518 us; speedup vs baseline: 1.1799x; 1.0275x over previous
//
#include <hip/hip_runtime.h>
#include <math.h>
#include <stdint.h>

#define BATCH 64
#define SEQ   101
#define HID   512
#define NKQ   100      // N*K
#define KCLS  10
#define INV_TEMP 0.04419417382415922f   // 1/sqrt(512)
#define SPAD  128      // padded S for MFMA tiles

typedef short bf16x8 __attribute__((ext_vector_type(8)));
typedef float f32x4  __attribute__((ext_vector_type(4)));

// workspace layout (bytes); total ~25.2 MB
#define WS_VTH 0
#define WS_VTL (WS_VTH + (size_t)BATCH*HID*SPAD*2)
#define WS_AH  (WS_VTL + (size_t)BATCH*HID*SPAD*2)
#define WS_AL  (WS_AH  + (size_t)BATCH*SPAD*SPAD*2)
#define WS_MH  (WS_AL  + (size_t)BATCH*SPAD*SPAD*2)
#define WS_ML  (WS_MH  + (size_t)BATCH*SPAD*SPAD*2)

// truncation split: x == hi + lo to ~2^-16 rel; (float)hi and x-hi exact
__device__ inline void split_bf16(float x, short& hi, short& lo) {
    uint32_t u = __builtin_bit_cast(uint32_t, x);
    hi = (short)(u >> 16);
    float hf = __builtin_bit_cast(float, u & 0xFFFF0000u);
    float l  = x - hf;
    lo = (short)(__builtin_bit_cast(uint32_t, l) >> 16);
}

// ---------------- P: vT hi/lo bf16, [b][h][j] with j padded to 128 ----------
__global__ __launch_bounds__(256)
void transpose_v(const float* __restrict__ v, short* __restrict__ vth,
                 short* __restrict__ vtl) {
    __shared__ float tile[SEQ][132];
    const int b = blockIdx.y, hc = blockIdx.x * 128;
    const float* vb = v + (size_t)b * SEQ * HID + hc;
    for (int f = threadIdx.x; f < SEQ * 32; f += 256) {
        int r = f >> 5, c = (f & 31) << 2;
        *(float4*)&tile[r][c] = *(const float4*)(vb + (size_t)r * HID + c);
    }
    __syncthreads();
    const int hl = threadIdx.x >> 1;            // 0..127
    const int j0 = (threadIdx.x & 1) * 64;
    const size_t rowo = ((size_t)b * HID + hc + hl) * SPAD + j0;
    for (int jj = 0; jj < 64; jj += 4) {
        short4 hv, lv;
        short h0,l0,h1,l1,h2,l2,h3,l3;
        int j = j0 + jj;
        split_bf16(j + 0 < SEQ ? tile[j + 0][hl] : 0.f, h0, l0);
        split_bf16(j + 1 < SEQ ? tile[j + 1][hl] : 0.f, h1, l1);
        split_bf16(j + 2 < SEQ ? tile[j + 2][hl] : 0.f, h2, l2);
        split_bf16(j + 3 < SEQ ? tile[j + 3][hl] : 0.f, h3, l3);
        hv.x = h0; hv.y = h1; hv.z = h2; hv.w = h3;
        lv.x = l0; lv.y = l1; lv.z = l2; lv.w = l3;
        *(short4*)(vth + rowo + jj) = hv;
        *(short4*)(vtl + rowo + jj) = lv;
    }
}

// ---------------- K1: scores = q k^T via MFMA (hi/lo split) -----------------
// grid (4 i-groups of 32, BATCH), block 256 (4 waves). Wave w: j in [32w,32w+32).
__global__ __launch_bounds__(256)
void qk_mfma(const float* __restrict__ q, const float* __restrict__ k,
             float* __restrict__ sc) {
    const int b = blockIdx.y, i0 = blockIdx.x * 32;
    const int wv = threadIdx.x >> 6, lane = threadIdx.x & 63;
    const int m  = lane & 15;            // row/col within tile
    const int kq = (lane >> 4) * 8;      // k offset within 32-step
    const int j0 = wv * 32;
    const float* qb = q + (size_t)b * SEQ * HID;
    const float* kb = k + (size_t)b * SEQ * HID;

    f32x4 acc[2][2] = {};
    for (int ks = 0; ks < HID; ks += 32) {
        bf16x8 ah[2], al[2], bh[2], bl[2];
        #pragma unroll
        for (int it = 0; it < 2; ++it) {
            const int row = i0 + it * 16 + m;
            float x[8];
            if (row < SEQ) {
                float4 u0 = *(const float4*)(qb + (size_t)row * HID + ks + kq);
                float4 u1 = *(const float4*)(qb + (size_t)row * HID + ks + kq + 4);
                x[0]=u0.x; x[1]=u0.y; x[2]=u0.z; x[3]=u0.w;
                x[4]=u1.x; x[5]=u1.y; x[6]=u1.z; x[7]=u1.w;
            } else {
                #pragma unroll
                for (int e = 0; e < 8; ++e) x[e] = 0.f;
            }
            #pragma unroll
            for (int e = 0; e < 8; ++e) { short h,l; split_bf16(x[e],h,l); ah[it][e]=h; al[it][e]=l; }
        }
        #pragma unroll
        for (int jt = 0; jt < 2; ++jt) {
            const int row = j0 + jt * 16 + m;
            float x[8];
            if (row < SEQ) {
                float4 u0 = *(const float4*)(kb + (size_t)row * HID + ks + kq);
                float4 u1 = *(const float4*)(kb + (size_t)row * HID + ks + kq + 4);
                x[0]=u0.x; x[1]=u0.y; x[2]=u0.z; x[3]=u0.w;
                x[4]=u1.x; x[5]=u1.y; x[6]=u1.z; x[7]=u1.w;
            } else {
                #pragma unroll
                for (int e = 0; e < 8; ++e) x[e] = 0.f;
            }
            #pragma unroll
            for (int e = 0; e < 8; ++e) { short h,l; split_bf16(x[e],h,l); bh[jt][e]=h; bl[jt][e]=l; }
        }
        #pragma unroll
        for (int it = 0; it < 2; ++it)
            #pragma unroll
            for (int jt = 0; jt < 2; ++jt) {
                acc[it][jt] = __builtin_amdgcn_mfma_f32_16x16x32_bf16(ah[it], bh[jt], acc[it][jt], 0, 0, 0);
                acc[it][jt] = __builtin_amdgcn_mfma_f32_16x16x32_bf16(ah[it], bl[jt], acc[it][jt], 0, 0, 0);
                acc[it][jt] = __builtin_amdgcn_mfma_f32_16x16x32_bf16(al[it], bh[jt], acc[it][jt], 0, 0, 0);
            }
    }
    const int col = lane & 15, rq = (lane >> 4) * 4;
    #pragma unroll
    for (int it = 0; it < 2; ++it)
        #pragma unroll
        for (int jt = 0; jt < 2; ++jt)
            #pragma unroll
            for (int r = 0; r < 4; ++r) {
                const int i = i0 + it * 16 + rq + r;
                const int j = j0 + jt * 16 + col;
                if (i < SEQ && j < SEQ)
                    sc[((size_t)b * SEQ + i) * SEQ + j] = acc[it][jt][r];
            }
}

// ---------------- K2: softmax + bf16 hi/lo attn + class-masked attn ---------
__global__ __launch_bounds__(256)
void softmax_rows(float* __restrict__ attn, short* __restrict__ ah,
                  short* __restrict__ al, short* __restrict__ mh,
                  short* __restrict__ ml) {
    const int lane = threadIdx.x & 63, wv = threadIdx.x >> 6;
    const int row = blockIdx.x * 4 + wv;   // 0..6463 = b*101+i
    const int b = row / SEQ, i = row - b * SEQ;
    float* p = attn + (size_t)row * SEQ;
    float s0 = (lane < SEQ) ? p[lane] * INV_TEMP : -1e30f;
    float s1 = (lane + 64 < SEQ) ? p[lane + 64] * INV_TEMP : -1e30f;
    float mx = fmaxf(s0, s1);
    #pragma unroll
    for (int off = 1; off < 64; off <<= 1) mx = fmaxf(mx, __shfl_xor(mx, off));
    float e0 = __expf(s0 - mx), e1 = __expf(s1 - mx);
    float sum = e0 + e1;
    #pragma unroll
    for (int off = 1; off < 64; off <<= 1) sum += __shfl_xor(sum, off);
    const float inv = 1.f / sum;
    float a0 = e0 * inv, a1 = e1 * inv;
    if (lane < SEQ) p[lane] = a0;
    if (lane + 64 < SEQ) p[lane + 64] = a1;

    const size_t ro = ((size_t)b * SPAD + i) * SPAD;
    const int ci = i / KCLS;
    {   // j = lane
        const int j = lane;
        float a = (j < SEQ) ? a0 : 0.f;
        short h, l; split_bf16(a, h, l);
        ah[ro + j] = h; al[ro + j] = l;
        bool msk = (j < SEQ) && ((j / KCLS) == ci);
        mh[ro + j] = msk ? h : (short)0;
        ml[ro + j] = msk ? l : (short)0;
    }
    {   // j = lane + 64
        const int j = lane + 64;
        float a = (j < SEQ) ? a1 : 0.f;
        short h, l; split_bf16(a, h, l);
        ah[ro + j] = h; al[ro + j] = l;
        bool msk = (j < SEQ) && ((j / KCLS) == ci);
        mh[ro + j] = msk ? h : (short)0;
        ml[ro + j] = msk ? l : (short)0;
    }
}

// ---------------- K3: T = attn@v, U = amask@v via MFMA + fused epilogue -----
// grid (4 h-groups of 128, 4 i-groups of 32, BATCH), block 256.
// Wave w: h in [h0+32w, +32). out = w2*T + (w1-w2)*U + corrections.
__global__ __launch_bounds__(256)
void out_mfma(const float* __restrict__ v, const float* __restrict__ aw,
              const float* __restrict__ attn,
              const short* __restrict__ ah, const short* __restrict__ al,
              const short* __restrict__ mh, const short* __restrict__ ml,
              const short* __restrict__ vth, const short* __restrict__ vtl,
              float* __restrict__ out) {
    const int b = blockIdx.z, i0 = blockIdx.y * 32, h0 = blockIdx.x * 128;
    const int wv = threadIdx.x >> 6, lane = threadIdx.x & 63;
    const int m  = lane & 15;
    const int kq = (lane >> 4) * 8;
    const int hw = h0 + wv * 32;

    f32x4 T[2][2] = {}, U[2][2] = {};
    for (int ks = 0; ks < SPAD; ks += 32) {
        bf16x8 Ah[2], Al[2], Mh[2], Ml[2], Bh[2], Bl[2];
        #pragma unroll
        for (int it = 0; it < 2; ++it) {
            const size_t ro = ((size_t)b * SPAD + i0 + it * 16 + m) * SPAD + ks + kq;
            Ah[it] = *(const bf16x8*)(ah + ro);
            Al[it] = *(const bf16x8*)(al + ro);
            Mh[it] = *(const bf16x8*)(mh + ro);
            Ml[it] = *(const bf16x8*)(ml + ro);
        }
        #pragma unroll
        for (int ht = 0; ht < 2; ++ht) {
            const size_t vo = ((size_t)b * HID + hw + ht * 16 + m) * SPAD + ks + kq;
            Bh[ht] = *(const bf16x8*)(vth + vo);
            Bl[ht] = *(const bf16x8*)(vtl + vo);
        }
        #pragma unroll
        for (int it = 0; it < 2; ++it)
            #pragma unroll
            for (int ht = 0; ht < 2; ++ht) {
                T[it][ht] = __builtin_amdgcn_mfma_f32_16x16x32_bf16(Ah[it], Bh[ht], T[it][ht], 0, 0, 0);
                T[it][ht] = __builtin_amdgcn_mfma_f32_16x16x32_bf16(Ah[it], Bl[ht], T[it][ht], 0, 0, 0);
                T[it][ht] = __builtin_amdgcn_mfma_f32_16x16x32_bf16(Al[it], Bh[ht], T[it][ht], 0, 0, 0);
                U[it][ht] = __builtin_amdgcn_mfma_f32_16x16x32_bf16(Mh[it], Bh[ht], U[it][ht], 0, 0, 0);
                U[it][ht] = __builtin_amdgcn_mfma_f32_16x16x32_bf16(Mh[it], Bl[ht], U[it][ht], 0, 0, 0);
                U[it][ht] = __builtin_amdgcn_mfma_f32_16x16x32_bf16(Ml[it], Bh[ht], U[it][ht], 0, 0, 0);
            }
    }

    const int col = lane & 15, rq = (lane >> 4) * 4;
    const float* ab = attn + (size_t)b * SEQ * SEQ;
    #pragma unroll
    for (int ht = 0; ht < 2; ++ht) {
        const int h = hw + ht * 16 + col;
        const float w0 = aw[0 * HID + h], w1 = aw[1 * HID + h], w2 = aw[2 * HID + h];
        const float w3 = aw[3 * HID + h], w4 = aw[4 * HID + h], w5 = aw[5 * HID + h];
        const float vN = v[((size_t)b * SEQ + NKQ) * HID + h];
        #pragma unroll
        for (int it = 0; it < 2; ++it)
            #pragma unroll
            for (int r = 0; r < 4; ++r) {
                const int i = i0 + it * 16 + rq + r;
                if (i >= SEQ) continue;
                const float t = T[it][ht][r], u = U[it][ht][r];
                const float aiN = ab[(size_t)i * SEQ + NKQ];
                float o;
                if (i < NKQ) {
                    const float aii = ab[(size_t)i * SEQ + i];
                    const float vi  = v[((size_t)b * SEQ + i) * HID + h];
                    o = w2 * t + (w1 - w2) * u + (w0 - w1) * aii * vi + (w3 - w2) * aiN * vN;
                } else {
                    o = w4 * t + (w5 - w4) * aiN * vN;
                }
                out[((size_t)b * SEQ + i) * HID + h] = o;
            }
    }
}

extern "C" void kernel_launch(void* const* d_in, const int* in_sizes, int n_in,
                              void* d_out, int out_size, void* d_ws, size_t ws_size,
                              hipStream_t stream) {
    const float* q  = (const float*)d_in[0];
    const float* k  = (const float*)d_in[1];
    const float* v  = (const float*)d_in[2];
    const float* aw = (const float*)d_in[3];
    float* out  = (float*)d_out;
    float* attn = out + (size_t)BATCH * SEQ * HID;   // tuple output: [out | attn]

    char* ws = (char*)d_ws;
    short* vth = (short*)(ws + WS_VTH);
    short* vtl = (short*)(ws + WS_VTL);
    short* ahp = (short*)(ws + WS_AH);
    short* alp = (short*)(ws + WS_AL);
    short* mhp = (short*)(ws + WS_MH);
    short* mlp = (short*)(ws + WS_ML);

    dim3 blk(256);
    transpose_v<<<dim3(4, BATCH), blk, 0, stream>>>(v, vth, vtl);
    qk_mfma<<<dim3(4, BATCH), blk, 0, stream>>>(q, k, attn);   // raw scores
    softmax_rows<<<dim3(BATCH * SEQ / 4), blk, 0, stream>>>(attn, ahp, alp, mhp, mlp);
    out_mfma<<<dim3(4, 4, BATCH), blk, 0, stream>>>(v, aw, attn, ahp, alp, mhp, mlp,
                                                    vth, vtl, out);
}

// Round 4
// 133.903 us; speedup vs baseline: 1.4496x; 1.2286x over previous
//
#include <hip/hip_runtime.h>
#include <math.h>
#include <stdint.h>

#define BATCH 64
#define SEQ   101
#define HID   512
#define NKQ   100      // N*K
#define KCLS  10
#define INV_TEMP 0.04419417382415922f   // 1/sqrt(512)
#define SPAD  128      // padded j for MFMA

typedef short bf16x8 __attribute__((ext_vector_type(8)));
typedef float f32x4  __attribute__((ext_vector_type(4)));

// truncation split: x == hi + lo to ~2^-16 rel
__device__ inline void split_bf16(float x, short& hi, short& lo) {
    uint32_t u = __builtin_bit_cast(uint32_t, x);
    hi = (short)(u >> 16);
    float hf = __builtin_bit_cast(float, u & 0xFFFF0000u);
    float l  = x - hf;
    lo = (short)(__builtin_bit_cast(uint32_t, l) >> 16);
}

// One block = (batch b, 32 query rows). 256 threads = 4 waves.
// Phase 1: QK^T (hi/lo bf16 MFMA, fragments straight from global fp32)
// Phase 2: block-local softmax -> attn global + LDS bf16 hi/lo (+class-masked)
// Phase 3: T = attn@v, U = amask@v (MFMA; B-frags gathered from global v)
// Phase 4: fused region-decomposed epilogue.
__global__ __launch_bounds__(256)
void fused_attn(const float* __restrict__ q, const float* __restrict__ k,
                const float* __restrict__ v, const float* __restrict__ aw,
                float* __restrict__ out, float* __restrict__ attn) {
    __shared__ float sc[32][132];        // fp32 scores -> normalized attn
    __shared__ short ah_s[32][136];      // attn hi
    __shared__ short al_s[32][136];      // attn lo
    __shared__ short mh_s[32][136];      // class-masked hi
    __shared__ short ml_s[32][136];      // class-masked lo

    const int b   = blockIdx.y;
    const int i0  = blockIdx.x * 32;
    const int tid = threadIdx.x;
    const int wv  = tid >> 6, lane = tid & 63;
    const int m   = lane & 15;
    const int kq  = (lane >> 4) * 8;
    const int col = lane & 15, rq = (lane >> 4) * 4;

    const float* qb = q + (size_t)b * SEQ * HID;
    const float* kb = k + (size_t)b * SEQ * HID;
    const float* vb = v + (size_t)b * SEQ * HID;

    // ---------------- Phase 1: QK^T ----------------
    {
        const int j0w = wv * 32;
        f32x4 acc[2][2] = {};
        for (int ks = 0; ks < HID; ks += 32) {
            bf16x8 qh[2], ql[2], kh[2], kl[2];
            #pragma unroll
            for (int it = 0; it < 2; ++it) {
                const int row = i0 + it * 16 + m;
                float x[8];
                if (row < SEQ) {
                    float4 u0 = *(const float4*)(qb + (size_t)row * HID + ks + kq);
                    float4 u1 = *(const float4*)(qb + (size_t)row * HID + ks + kq + 4);
                    x[0]=u0.x; x[1]=u0.y; x[2]=u0.z; x[3]=u0.w;
                    x[4]=u1.x; x[5]=u1.y; x[6]=u1.z; x[7]=u1.w;
                } else {
                    #pragma unroll
                    for (int e = 0; e < 8; ++e) x[e] = 0.f;
                }
                #pragma unroll
                for (int e = 0; e < 8; ++e) { short h,l; split_bf16(x[e],h,l); qh[it][e]=h; ql[it][e]=l; }
            }
            #pragma unroll
            for (int jt = 0; jt < 2; ++jt) {
                const int row = j0w + jt * 16 + m;
                float x[8];
                if (row < SEQ) {
                    float4 u0 = *(const float4*)(kb + (size_t)row * HID + ks + kq);
                    float4 u1 = *(const float4*)(kb + (size_t)row * HID + ks + kq + 4);
                    x[0]=u0.x; x[1]=u0.y; x[2]=u0.z; x[3]=u0.w;
                    x[4]=u1.x; x[5]=u1.y; x[6]=u1.z; x[7]=u1.w;
                } else {
                    #pragma unroll
                    for (int e = 0; e < 8; ++e) x[e] = 0.f;
                }
                #pragma unroll
                for (int e = 0; e < 8; ++e) { short h,l; split_bf16(x[e],h,l); kh[jt][e]=h; kl[jt][e]=l; }
            }
            #pragma unroll
            for (int it = 0; it < 2; ++it)
                #pragma unroll
                for (int jt = 0; jt < 2; ++jt) {
                    acc[it][jt] = __builtin_amdgcn_mfma_f32_16x16x32_bf16(qh[it], kh[jt], acc[it][jt], 0, 0, 0);
                    acc[it][jt] = __builtin_amdgcn_mfma_f32_16x16x32_bf16(qh[it], kl[jt], acc[it][jt], 0, 0, 0);
                    acc[it][jt] = __builtin_amdgcn_mfma_f32_16x16x32_bf16(ql[it], kh[jt], acc[it][jt], 0, 0, 0);
                }
        }
        #pragma unroll
        for (int it = 0; it < 2; ++it)
            #pragma unroll
            for (int jt = 0; jt < 2; ++jt)
                #pragma unroll
                for (int r = 0; r < 4; ++r)
                    sc[it * 16 + rq + r][j0w + jt * 16 + col] = acc[it][jt][r];
    }
    __syncthreads();

    // ---------------- Phase 2: softmax + bf16 conversion ----------------
    {
        const int row = tid >> 3, t8 = tid & 7;
        const int gi  = i0 + row;
        float mx = -1e30f;
        for (int j = t8; j < SEQ; j += 8) {
            float s = sc[row][j] * INV_TEMP;
            sc[row][j] = s;
            mx = fmaxf(mx, s);
        }
        #pragma unroll
        for (int off = 1; off < 8; off <<= 1) mx = fmaxf(mx, __shfl_xor(mx, off));
        float sum = 0.f;
        for (int j = t8; j < SEQ; j += 8) {
            float e = __expf(sc[row][j] - mx);
            sc[row][j] = e;
            sum += e;
        }
        #pragma unroll
        for (int off = 1; off < 8; off <<= 1) sum += __shfl_xor(sum, off);
        const float inv = 1.f / sum;
        const int ci = gi / KCLS;
        float* arow = attn + ((size_t)b * SEQ + gi) * SEQ;
        for (int j = t8; j < SEQ; j += 8) {
            float a = sc[row][j] * inv;
            sc[row][j] = a;
            if (gi < SEQ) arow[j] = a;
            short h, l; split_bf16(a, h, l);
            ah_s[row][j] = h; al_s[row][j] = l;
            bool msk = (j / KCLS) == ci;
            mh_s[row][j] = msk ? h : (short)0;
            ml_s[row][j] = msk ? l : (short)0;
        }
        for (int j = SEQ + t8; j < 136; j += 8) {   // zero pad j in [101,136)
            ah_s[row][j] = 0; al_s[row][j] = 0;
            mh_s[row][j] = 0; ml_s[row][j] = 0;
        }
    }
    __syncthreads();

    // ---------------- Phase 3+4: PV MFMA + epilogue (two h-halves) -------
    const int hw = wv * 128;   // wave's 128-h strip
    #pragma unroll
    for (int half = 0; half < 2; ++half) {
        f32x4 T[2][4] = {}, U[2][4] = {};
        #pragma unroll
        for (int ks = 0; ks < SPAD; ks += 32) {
            bf16x8 Ah[2], Al[2], Mh[2], Ml[2];
            #pragma unroll
            for (int it = 0; it < 2; ++it) {
                const int il = it * 16 + m;
                Ah[it] = *(const bf16x8*)&ah_s[il][ks + kq];
                Al[it] = *(const bf16x8*)&al_s[il][ks + kq];
                Mh[it] = *(const bf16x8*)&mh_s[il][ks + kq];
                Ml[it] = *(const bf16x8*)&ml_s[il][ks + kq];
            }
            #pragma unroll
            for (int ht4 = 0; ht4 < 4; ++ht4) {
                const int h = hw + (half * 4 + ht4) * 16 + m;
                float x[8];
                #pragma unroll
                for (int e = 0; e < 8; ++e) {
                    const int j = ks + kq + e;
                    x[e] = (j < SEQ) ? vb[(size_t)j * HID + h] : 0.f;
                }
                bf16x8 Bh, Bl;
                #pragma unroll
                for (int e = 0; e < 8; ++e) { short hh,ll; split_bf16(x[e],hh,ll); Bh[e]=hh; Bl[e]=ll; }
                #pragma unroll
                for (int it = 0; it < 2; ++it) {
                    T[it][ht4] = __builtin_amdgcn_mfma_f32_16x16x32_bf16(Ah[it], Bh, T[it][ht4], 0, 0, 0);
                    T[it][ht4] = __builtin_amdgcn_mfma_f32_16x16x32_bf16(Ah[it], Bl, T[it][ht4], 0, 0, 0);
                    T[it][ht4] = __builtin_amdgcn_mfma_f32_16x16x32_bf16(Al[it], Bh, T[it][ht4], 0, 0, 0);
                    U[it][ht4] = __builtin_amdgcn_mfma_f32_16x16x32_bf16(Mh[it], Bh, U[it][ht4], 0, 0, 0);
                    U[it][ht4] = __builtin_amdgcn_mfma_f32_16x16x32_bf16(Mh[it], Bl, U[it][ht4], 0, 0, 0);
                    U[it][ht4] = __builtin_amdgcn_mfma_f32_16x16x32_bf16(Ml[it], Bh, U[it][ht4], 0, 0, 0);
                }
            }
        }
        // epilogue for this half
        #pragma unroll
        for (int ht4 = 0; ht4 < 4; ++ht4) {
            const int h = hw + (half * 4 + ht4) * 16 + col;
            const float w0 = aw[0 * HID + h], w1 = aw[1 * HID + h], w2 = aw[2 * HID + h];
            const float w3 = aw[3 * HID + h], w4 = aw[4 * HID + h], w5 = aw[5 * HID + h];
            const float vN = vb[(size_t)NKQ * HID + h];
            #pragma unroll
            for (int it = 0; it < 2; ++it)
                #pragma unroll
                for (int r = 0; r < 4; ++r) {
                    const int il = it * 16 + rq + r;
                    const int i  = i0 + il;
                    if (i >= SEQ) continue;
                    const float t = T[it][ht4][r], u = U[it][ht4][r];
                    const float aiN = sc[il][NKQ];
                    float o;
                    if (i < NKQ) {
                        const float aii = sc[il][i];
                        const float vi  = vb[(size_t)i * HID + h];
                        o = w2 * t + (w1 - w2) * u + (w0 - w1) * aii * vi + (w3 - w2) * aiN * vN;
                    } else {
                        o = w4 * t + (w5 - w4) * aiN * vN;
                    }
                    out[((size_t)b * SEQ + i) * HID + h] = o;
                }
        }
    }
}

extern "C" void kernel_launch(void* const* d_in, const int* in_sizes, int n_in,
                              void* d_out, int out_size, void* d_ws, size_t ws_size,
                              hipStream_t stream) {
    const float* q  = (const float*)d_in[0];
    const float* k  = (const float*)d_in[1];
    const float* v  = (const float*)d_in[2];
    const float* aw = (const float*)d_in[3];
    float* out  = (float*)d_out;
    float* attn = out + (size_t)BATCH * SEQ * HID;   // tuple output: [out | attn]

    fused_attn<<<dim3(4, BATCH), dim3(256), 0, stream>>>(q, k, v, aw, out, attn);
}

// Round 5
// 127.331 us; speedup vs baseline: 1.5244x; 1.0516x over previous
//
#include <hip/hip_runtime.h>
#include <math.h>
#include <stdint.h>

#define BATCH 64
#define SEQ   101
#define HID   512
#define NKQ   100      // N*K
#define KCLS  10
#define INV_TEMP 0.04419417382415922f   // 1/sqrt(512)
#define SPAD  128      // padded j for MFMA

typedef short bf16x8 __attribute__((ext_vector_type(8)));
typedef float f32x4  __attribute__((ext_vector_type(4)));

// truncation split: x == hi + lo to ~2^-17 rel
__device__ inline void split_bf16(float x, short& hi, short& lo) {
    uint32_t u = __builtin_bit_cast(uint32_t, x);
    hi = (short)(u >> 16);
    float hf = __builtin_bit_cast(float, u & 0xFFFF0000u);
    float l  = x - hf;
    lo = (short)(__builtin_bit_cast(uint32_t, l) >> 16);
}

// One block = (batch b, 16 query rows). 512 threads = 8 waves.
// Wave w: P1 computes j-strip [16w,16w+16); P3 computes h-strip [64w,64w+64).
// grid (7,64) = 448 blocks -> ~1.75 blocks/CU, 3-4 waves/SIMD (latency hiding).
__global__ __launch_bounds__(512, 4)
void fused_attn(const float* __restrict__ q, const float* __restrict__ k,
                const float* __restrict__ v, const float* __restrict__ aw,
                float* __restrict__ out, float* __restrict__ attn) {
    __shared__ float sc[16][132];        // fp32 scores -> normalized attn
    __shared__ short ah_s[16][136];      // attn hi (A-operand layout)
    __shared__ short al_s[16][136];      // attn lo
    __shared__ short mh_s[16][136];      // class-masked attn hi

    const int b   = blockIdx.y;
    const int i0  = blockIdx.x * 16;
    const int tid = threadIdx.x;
    const int wv  = tid >> 6, lane = tid & 63;
    const int m   = lane & 15;           // A-row / B-col / C-col index
    const int kq  = (lane >> 4) * 8;     // k-offset within 32-step
    const int rq  = (lane >> 4) * 4;     // C-row quad base

    const float* qb = q + (size_t)b * SEQ * HID;
    const float* kb = k + (size_t)b * SEQ * HID;
    const float* vb = v + (size_t)b * SEQ * HID;

    // ---------------- Phase 1: QK^T (hi/lo bf16 MFMA) ----------------
    {
        const int j0w = wv * 16;
        const int qrow = i0 + m;
        const int krow = j0w + m;
        f32x4 acc = {};
        for (int ks = 0; ks < HID; ks += 32) {
            float x[8];
            bf16x8 qh, ql, kh, kl;
            if (qrow < SEQ) {
                float4 u0 = *(const float4*)(qb + (size_t)qrow * HID + ks + kq);
                float4 u1 = *(const float4*)(qb + (size_t)qrow * HID + ks + kq + 4);
                x[0]=u0.x; x[1]=u0.y; x[2]=u0.z; x[3]=u0.w;
                x[4]=u1.x; x[5]=u1.y; x[6]=u1.z; x[7]=u1.w;
            } else {
                #pragma unroll
                for (int e = 0; e < 8; ++e) x[e] = 0.f;
            }
            #pragma unroll
            for (int e = 0; e < 8; ++e) { short h,l; split_bf16(x[e],h,l); qh[e]=h; ql[e]=l; }
            if (krow < SEQ) {
                float4 u0 = *(const float4*)(kb + (size_t)krow * HID + ks + kq);
                float4 u1 = *(const float4*)(kb + (size_t)krow * HID + ks + kq + 4);
                x[0]=u0.x; x[1]=u0.y; x[2]=u0.z; x[3]=u0.w;
                x[4]=u1.x; x[5]=u1.y; x[6]=u1.z; x[7]=u1.w;
            } else {
                #pragma unroll
                for (int e = 0; e < 8; ++e) x[e] = 0.f;
            }
            #pragma unroll
            for (int e = 0; e < 8; ++e) { short h,l; split_bf16(x[e],h,l); kh[e]=h; kl[e]=l; }
            acc = __builtin_amdgcn_mfma_f32_16x16x32_bf16(qh, kh, acc, 0, 0, 0);
            acc = __builtin_amdgcn_mfma_f32_16x16x32_bf16(qh, kl, acc, 0, 0, 0);
            acc = __builtin_amdgcn_mfma_f32_16x16x32_bf16(ql, kh, acc, 0, 0, 0);
        }
        #pragma unroll
        for (int r = 0; r < 4; ++r)
            sc[rq + r][j0w + m] = acc[r];
    }
    __syncthreads();

    // ---------------- Phase 2: softmax + bf16 conversion ----------------
    {
        const int row = tid >> 5, t32 = tid & 31;
        const int gi  = i0 + row;
        float mx = -1e30f;
        for (int j = t32; j < SEQ; j += 32) {
            float s = sc[row][j] * INV_TEMP;
            sc[row][j] = s;
            mx = fmaxf(mx, s);
        }
        #pragma unroll
        for (int off = 1; off < 32; off <<= 1) mx = fmaxf(mx, __shfl_xor(mx, off));
        float sum = 0.f;
        for (int j = t32; j < SEQ; j += 32) {
            float e = __expf(sc[row][j] - mx);
            sc[row][j] = e;
            sum += e;
        }
        #pragma unroll
        for (int off = 1; off < 32; off <<= 1) sum += __shfl_xor(sum, off);
        const float inv = 1.f / sum;
        const int ci = gi / KCLS;
        float* arow = attn + ((size_t)b * SEQ + gi) * SEQ;
        for (int j = t32; j < SEQ; j += 32) {
            float a = sc[row][j] * inv;
            sc[row][j] = a;
            if (gi < SEQ) arow[j] = a;
            short h, l; split_bf16(a, h, l);
            ah_s[row][j] = h; al_s[row][j] = l;
            mh_s[row][j] = ((j / KCLS) == ci) ? h : (short)0;
        }
        for (int j = SEQ + t32; j < 136; j += 32) {   // zero pad
            ah_s[row][j] = 0; al_s[row][j] = 0; mh_s[row][j] = 0;
        }
    }
    __syncthreads();

    // ---------------- Phase 3: T = attn@v (hi/lo), U = amask@v (single) -----
    const int hw = wv * 64;
    f32x4 T[4] = {}, U[4] = {};
    for (int ks = 0; ks < SPAD; ks += 32) {
        const bf16x8 Ah = *(const bf16x8*)&ah_s[m][ks + kq];
        const bf16x8 Al = *(const bf16x8*)&al_s[m][ks + kq];
        const bf16x8 Mh = *(const bf16x8*)&mh_s[m][ks + kq];
        #pragma unroll
        for (int ht = 0; ht < 4; ++ht) {
            const int h = hw + ht * 16 + m;
            float x[8];
            #pragma unroll
            for (int e = 0; e < 8; ++e) {
                const int j = ks + kq + e;
                x[e] = (j < SEQ) ? vb[(size_t)j * HID + h] : 0.f;
            }
            bf16x8 Bh, Bl;
            #pragma unroll
            for (int e = 0; e < 8; ++e) { short hh,ll; split_bf16(x[e],hh,ll); Bh[e]=hh; Bl[e]=ll; }
            T[ht] = __builtin_amdgcn_mfma_f32_16x16x32_bf16(Ah, Bh, T[ht], 0, 0, 0);
            T[ht] = __builtin_amdgcn_mfma_f32_16x16x32_bf16(Ah, Bl, T[ht], 0, 0, 0);
            T[ht] = __builtin_amdgcn_mfma_f32_16x16x32_bf16(Al, Bh, T[ht], 0, 0, 0);
            U[ht] = __builtin_amdgcn_mfma_f32_16x16x32_bf16(Mh, Bh, U[ht], 0, 0, 0);
        }
    }

    // ---------------- Phase 4: fused region-decomposed epilogue -------------
    #pragma unroll
    for (int ht = 0; ht < 4; ++ht) {
        const int h = hw + ht * 16 + m;
        const float w0 = aw[0 * HID + h], w1 = aw[1 * HID + h], w2 = aw[2 * HID + h];
        const float w3 = aw[3 * HID + h], w4 = aw[4 * HID + h], w5 = aw[5 * HID + h];
        const float vN = vb[(size_t)NKQ * HID + h];
        #pragma unroll
        for (int r = 0; r < 4; ++r) {
            const int il = rq + r;
            const int i  = i0 + il;
            if (i >= SEQ) continue;
            const float t = T[ht][r], u = U[ht][r];
            const float aiN = sc[il][NKQ];
            float o;
            if (i < NKQ) {
                const float aii = sc[il][i];
                const float vi  = vb[(size_t)i * HID + h];
                o = w2 * t + (w1 - w2) * u + (w0 - w1) * aii * vi + (w3 - w2) * aiN * vN;
            } else {
                o = w4 * t + (w5 - w4) * aiN * vN;
            }
            out[((size_t)b * SEQ + i) * HID + h] = o;
        }
    }
}

extern "C" void kernel_launch(void* const* d_in, const int* in_sizes, int n_in,
                              void* d_out, int out_size, void* d_ws, size_t ws_size,
                              hipStream_t stream) {
    const float* q  = (const float*)d_in[0];
    const float* k  = (const float*)d_in[1];
    const float* v  = (const float*)d_in[2];
    const float* aw = (const float*)d_in[3];
    float* out  = (float*)d_out;
    float* attn = out + (size_t)BATCH * SEQ * HID;   // tuple output: [out | attn]

    fused_attn<<<dim3(7, BATCH), dim3(512), 0, stream>>>(q, k, v, aw, out, attn);
}

// Round 6
// 120.958 us; speedup vs baseline: 1.6048x; 1.0527x over previous
//
#include <hip/hip_runtime.h>
#include <math.h>
#include <stdint.h>

#define BATCH 64
#define SEQ   101
#define HID   512
#define NKQ   100      // N*K
#define KCLS  10
#define INV_TEMP 0.04419417382415922f   // 1/sqrt(512)
#define SPAD  128      // padded j for MFMA

typedef short bf16x8 __attribute__((ext_vector_type(8)));
typedef float f32x4  __attribute__((ext_vector_type(4)));

// truncation split: x == hi + lo to ~2^-17 rel
__device__ inline void split_bf16(float x, short& hi, short& lo) {
    uint32_t u = __builtin_bit_cast(uint32_t, x);
    hi = (short)(u >> 16);
    float hf = __builtin_bit_cast(float, u & 0xFFFF0000u);
    float l  = x - hf;
    lo = (short)(__builtin_bit_cast(uint32_t, l) >> 16);
}

// One block = (batch b, 16 query rows). 512 threads = 8 waves.
// XCD-aware mapping: grid is flat 448; b = id & 63, it = id >> 6. All 7 blocks
// of one b have ids = b (mod 64) -> same id mod 8 -> same XCD round-robin slot,
// so k[b]/v[b] re-reads hit that XCD's L2 (8 b's x ~420KB = 3.4MB < 4MB L2).
__global__ __launch_bounds__(512, 4)
void fused_attn(const float* __restrict__ q, const float* __restrict__ k,
                const float* __restrict__ v, const float* __restrict__ aw,
                float* __restrict__ out, float* __restrict__ attn) {
    __shared__ float sc[16][132];        // fp32 scores -> normalized attn
    __shared__ short ah_s[16][136];      // attn hi (A-operand layout)
    __shared__ short al_s[16][136];      // attn lo
    __shared__ short mh_s[16][136];      // class-masked attn hi

    const int b   = blockIdx.x & 63;
    const int i0  = (blockIdx.x >> 6) * 16;
    const int tid = threadIdx.x;
    const int wv  = tid >> 6, lane = tid & 63;
    const int m   = lane & 15;           // A-row / B-col / C-col index
    const int kq  = (lane >> 4) * 8;     // k-offset within 32-step
    const int rq  = (lane >> 4) * 4;     // C-row quad base

    const float* qb = q + (size_t)b * SEQ * HID;
    const float* kb = k + (size_t)b * SEQ * HID;
    const float* vb = v + (size_t)b * SEQ * HID;

    // ---------------- Phase 1: QK^T (hi/lo bf16 MFMA) ----------------
    {
        const int j0w = wv * 16;
        const int qrow = i0 + m;
        const int krow = j0w + m;
        f32x4 acc = {};
        for (int ks = 0; ks < HID; ks += 32) {
            float x[8];
            bf16x8 qh, ql, kh, kl;
            if (qrow < SEQ) {
                float4 u0 = *(const float4*)(qb + (size_t)qrow * HID + ks + kq);
                float4 u1 = *(const float4*)(qb + (size_t)qrow * HID + ks + kq + 4);
                x[0]=u0.x; x[1]=u0.y; x[2]=u0.z; x[3]=u0.w;
                x[4]=u1.x; x[5]=u1.y; x[6]=u1.z; x[7]=u1.w;
            } else {
                #pragma unroll
                for (int e = 0; e < 8; ++e) x[e] = 0.f;
            }
            #pragma unroll
            for (int e = 0; e < 8; ++e) { short h,l; split_bf16(x[e],h,l); qh[e]=h; ql[e]=l; }
            if (krow < SEQ) {
                float4 u0 = *(const float4*)(kb + (size_t)krow * HID + ks + kq);
                float4 u1 = *(const float4*)(kb + (size_t)krow * HID + ks + kq + 4);
                x[0]=u0.x; x[1]=u0.y; x[2]=u0.z; x[3]=u0.w;
                x[4]=u1.x; x[5]=u1.y; x[6]=u1.z; x[7]=u1.w;
            } else {
                #pragma unroll
                for (int e = 0; e < 8; ++e) x[e] = 0.f;
            }
            #pragma unroll
            for (int e = 0; e < 8; ++e) { short h,l; split_bf16(x[e],h,l); kh[e]=h; kl[e]=l; }
            acc = __builtin_amdgcn_mfma_f32_16x16x32_bf16(qh, kh, acc, 0, 0, 0);
            acc = __builtin_amdgcn_mfma_f32_16x16x32_bf16(qh, kl, acc, 0, 0, 0);
            acc = __builtin_amdgcn_mfma_f32_16x16x32_bf16(ql, kh, acc, 0, 0, 0);
        }
        #pragma unroll
        for (int r = 0; r < 4; ++r)
            sc[rq + r][j0w + m] = acc[r];
    }
    __syncthreads();

    // ---------------- Phase 2: softmax + bf16 conversion ----------------
    {
        const int row = tid >> 5, t32 = tid & 31;
        const int gi  = i0 + row;
        float mx = -1e30f;
        for (int j = t32; j < SEQ; j += 32) {
            float s = sc[row][j] * INV_TEMP;
            sc[row][j] = s;
            mx = fmaxf(mx, s);
        }
        #pragma unroll
        for (int off = 1; off < 32; off <<= 1) mx = fmaxf(mx, __shfl_xor(mx, off));
        float sum = 0.f;
        for (int j = t32; j < SEQ; j += 32) {
            float e = __expf(sc[row][j] - mx);
            sc[row][j] = e;
            sum += e;
        }
        #pragma unroll
        for (int off = 1; off < 32; off <<= 1) sum += __shfl_xor(sum, off);
        const float inv = 1.f / sum;
        const int ci = gi / KCLS;
        float* arow = attn + ((size_t)b * SEQ + gi) * SEQ;
        for (int j = t32; j < SEQ; j += 32) {
            float a = sc[row][j] * inv;
            sc[row][j] = a;
            if (gi < SEQ) arow[j] = a;
            short h, l; split_bf16(a, h, l);
            ah_s[row][j] = h; al_s[row][j] = l;
            mh_s[row][j] = ((j / KCLS) == ci) ? h : (short)0;
        }
        for (int j = SEQ + t32; j < 136; j += 32) {   // zero pad
            ah_s[row][j] = 0; al_s[row][j] = 0; mh_s[row][j] = 0;
        }
    }
    __syncthreads();

    // ---------------- Phase 3: T = attn@v (hi/lo), U = amask@v (single) -----
    const int hw = wv * 64;
    f32x4 T[4] = {}, U[4] = {};
    for (int ks = 0; ks < SPAD; ks += 32) {
        const bf16x8 Ah = *(const bf16x8*)&ah_s[m][ks + kq];
        const bf16x8 Al = *(const bf16x8*)&al_s[m][ks + kq];
        const bf16x8 Mh = *(const bf16x8*)&mh_s[m][ks + kq];
        #pragma unroll
        for (int ht = 0; ht < 4; ++ht) {
            const int h = hw + ht * 16 + m;
            float x[8];
            #pragma unroll
            for (int e = 0; e < 8; ++e) {
                const int j = ks + kq + e;
                x[e] = (j < SEQ) ? vb[(size_t)j * HID + h] : 0.f;
            }
            bf16x8 Bh, Bl;
            #pragma unroll
            for (int e = 0; e < 8; ++e) { short hh,ll; split_bf16(x[e],hh,ll); Bh[e]=hh; Bl[e]=ll; }
            T[ht] = __builtin_amdgcn_mfma_f32_16x16x32_bf16(Ah, Bh, T[ht], 0, 0, 0);
            T[ht] = __builtin_amdgcn_mfma_f32_16x16x32_bf16(Ah, Bl, T[ht], 0, 0, 0);
            T[ht] = __builtin_amdgcn_mfma_f32_16x16x32_bf16(Al, Bh, T[ht], 0, 0, 0);
            U[ht] = __builtin_amdgcn_mfma_f32_16x16x32_bf16(Mh, Bh, U[ht], 0, 0, 0);
        }
    }

    // ---------------- Phase 4: fused region-decomposed epilogue -------------
    #pragma unroll
    for (int ht = 0; ht < 4; ++ht) {
        const int h = hw + ht * 16 + m;
        const float w0 = aw[0 * HID + h], w1 = aw[1 * HID + h], w2 = aw[2 * HID + h];
        const float w3 = aw[3 * HID + h], w4 = aw[4 * HID + h], w5 = aw[5 * HID + h];
        const float vN = vb[(size_t)NKQ * HID + h];
        #pragma unroll
        for (int r = 0; r < 4; ++r) {
            const int il = rq + r;
            const int i  = i0 + il;
            if (i >= SEQ) continue;
            const float t = T[ht][r], u = U[ht][r];
            const float aiN = sc[il][NKQ];
            float o;
            if (i < NKQ) {
                const float aii = sc[il][i];
                const float vi  = vb[(size_t)i * HID + h];
                o = w2 * t + (w1 - w2) * u + (w0 - w1) * aii * vi + (w3 - w2) * aiN * vN;
            } else {
                o = w4 * t + (w5 - w4) * aiN * vN;
            }
            out[((size_t)b * SEQ + i) * HID + h] = o;
        }
    }
}

extern "C" void kernel_launch(void* const* d_in, const int* in_sizes, int n_in,
                              void* d_out, int out_size, void* d_ws, size_t ws_size,
                              hipStream_t stream) {
    const float* q  = (const float*)d_in[0];
    const float* k  = (const float*)d_in[1];
    const float* v  = (const float*)d_in[2];
    const float* aw = (const float*)d_in[3];
    float* out  = (float*)d_out;
    float* attn = out + (size_t)BATCH * SEQ * HID;   // tuple output: [out | attn]

    fused_attn<<<dim3(448), dim3(512), 0, stream>>>(q, k, v, aw, out, attn);
}